// Round 6
// baseline (247.094 us; speedup 1.0000x reference)
//
#include <hip/hip_runtime.h>
#include <hip/hip_cooperative_groups.h>

namespace cg = cooperative_groups;

#define EPS 1e-6f
#define IT 512           // clash i-tile (2 per thread, 256 threads)
#define JTL 64           // clash j-tile (LDS resident)
#define RATIO 8          // IT / JTL
#define WB 64            // within-residue blocks

static __device__ __forceinline__ float wave_reduce_add(float v) {
#pragma unroll
    for (int o = 32; o > 0; o >>= 1) v += __shfl_down(v, o, 64);
    return v;
}

// ws layout per batch (stride = NBP + 7 floats):
//   [0, NBP)       per-block pair-loss partials (clash + within blocks)
//   [NBP, NBP+6)   bonds: cn_num cn_den cacn_num cacn_den cnca_num cnca_den
//   [NBP+6]        atom-mask total
// Every slot written unconditionally every launch -> no zero-init needed.

__device__ void do_bonds(const float* __restrict__ P, const float* __restrict__ M,
                         const int* __restrict__ RT, const int* __restrict__ RI,
                         float* __restrict__ Wtail, int N, int A) {
    float n0 = 0.f, de0 = 0.f, n1 = 0.f, de1 = 0.f, n2 = 0.f, de2 = 0.f;
    for (int i = threadIdx.x; i < N - 1; i += blockDim.x) {
        float no_gap = (RI[i + 1] - RI[i] == 1) ? 1.f : 0.f;
        const float* ca0 = P + i * 42 + 3;
        const float* c0  = P + i * 42 + 6;
        const float* nn  = P + (i + 1) * 42 + 0;
        const float* ca1 = P + (i + 1) * 42 + 3;
        float m_ca0 = M[i * 14 + 1], m_c0 = M[i * 14 + 2];
        float m_nn = M[(i + 1) * 14 + 0], m_ca1 = M[(i + 1) * 14 + 1];

        float bx = nn[0] - c0[0], by = nn[1] - c0[1], bz = nn[2] - c0[2];
        float c_n_len = sqrtf(bx * bx + by * by + bz * bz + EPS);
        float pro = (RT[i + 1] == 14) ? 1.f : 0.f;
        float gt_len = (1.f - pro) * 1.329f + pro * 1.341f;
        float gt_std = (1.f - pro) * 0.014f + pro * 0.016f;
        float cnm = m_c0 * m_nn * no_gap;
        float dl = c_n_len - gt_len;
        float cne = sqrtf(dl * dl + EPS);
        n0 += cnm * fmaxf(cne - 12.f * gt_std, 0.f);
        de0 += cnm;

        float ax = ca0[0] - c0[0], ay = ca0[1] - c0[1], az = ca0[2] - c0[2];
        float ca_c_len = sqrtf(ax * ax + ay * ay + az * az + EPS);
        float ex = ca1[0] - nn[0], ey = ca1[1] - nn[1], ez = ca1[2] - nn[2];
        float n_ca_len = sqrtf(ex * ex + ey * ey + ez * ez + EPS);
        float inv_cn = 1.f / c_n_len, inv_ac = 1.f / ca_c_len, inv_nc = 1.f / n_ca_len;
        float ux = bx * inv_cn, uy = by * inv_cn, uz = bz * inv_cn;
        float cx = ax * inv_ac, cy = ay * inv_ac, cz = az * inv_ac;
        float wx = ex * inv_nc, wy = ey * inv_nc, wz = ez * inv_nc;

        float cacn = cx * ux + cy * uy + cz * uz;
        float m1 = m_ca0 * m_c0 * m_nn * no_gap;
        float t1 = cacn + 0.5203f;
        float e1 = sqrtf(t1 * t1 + EPS);
        n1 += m1 * fmaxf(e1 - 12.f * 0.0353f, 0.f);
        de1 += m1;

        float cnca = -(ux * wx + uy * wy + uz * wz);
        float m2 = m_c0 * m_nn * m_ca1 * no_gap;
        float t2 = cnca + 0.4473f;
        float e2 = sqrtf(t2 * t2 + EPS);
        n2 += m2 * fmaxf(e2 - 12.f * 0.0311f, 0.f);
        de2 += m2;
    }
    // atom-mask total (runs concurrent with clash blocks, pre-sync)
    float ms = 0.f;
    int A4 = A >> 2;
    const float4* M4 = (const float4*)M;
    for (int i = threadIdx.x; i < A4; i += blockDim.x) {
        float4 v = M4[i];
        ms += v.x + v.y + v.z + v.w;
    }
    if (threadIdx.x == 0) for (int i = A4 << 2; i < A; ++i) ms += M[i];

    n0 = wave_reduce_add(n0); de0 = wave_reduce_add(de0);
    n1 = wave_reduce_add(n1); de1 = wave_reduce_add(de1);
    n2 = wave_reduce_add(n2); de2 = wave_reduce_add(de2);
    ms = wave_reduce_add(ms);
    __shared__ float redb[28];
    int lane = threadIdx.x & 63, wid = threadIdx.x >> 6;
    if (lane == 0) {
        redb[wid * 7 + 0] = n0; redb[wid * 7 + 1] = de0; redb[wid * 7 + 2] = n1;
        redb[wid * 7 + 3] = de1; redb[wid * 7 + 4] = n2; redb[wid * 7 + 5] = de2;
        redb[wid * 7 + 6] = ms;
    }
    __syncthreads();
    if (threadIdx.x < 7) {
        Wtail[threadIdx.x] = redb[threadIdx.x] + redb[7 + threadIdx.x]
                           + redb[14 + threadIdx.x] + redb[21 + threadIdx.x];
    }
}

__device__ void do_within(const float* __restrict__ pos, const float* __restrict__ am,
                          const int* __restrict__ rtypes,
                          const float* __restrict__ lbt, const float* __restrict__ ubt,
                          float* __restrict__ slot, int N, int b, int wblk) {
    int total = N * 196;
    float sum = 0.f;
    for (int idx = wblk * blockDim.x + threadIdx.x; idx < total; idx += WB * blockDim.x) {
        int n = idx / 196;
        int p = idx - n * 196;
        int i = p / 14;
        int j = p - i * 14;
        if (i == j) continue;
        size_t bn = (size_t)b * N + n;
        int rt = rtypes[bn]; rt = rt < 20 ? rt : 20;
        const float* pi = pos + bn * 42 + i * 3;
        const float* pj = pos + bn * 42 + j * 3;
        float dx = pi[0] - pj[0], dy = pi[1] - pj[1], dz = pi[2] - pj[2];
        float d = sqrtf(dx * dx + dy * dy + dz * dz + 1e-8f);
        float lb = lbt[rt * 196 + p], ub = ubt[rt * 196 + p];
        float gate = (lb > 0.f || ub > 0.f) ? 1.f : 0.f;
        float m = am[bn * 14 + i] * am[bn * 14 + j] * gate;
        sum += (fmaxf(lb - d, 0.f) + fmaxf(d - ub, 0.f)) * m;
    }
    sum = wave_reduce_add(sum);
    __shared__ float red2[4];
    int lane = threadIdx.x & 63, wid = threadIdx.x >> 6;
    if (lane == 0) red2[wid] = sum;
    __syncthreads();
    if (threadIdx.x == 0) *slot = red2[0] + red2[1] + red2[2] + red2[3];
}

__device__ void do_clash(const float* __restrict__ P, const float* __restrict__ M,
                         const int* __restrict__ RT, const int* __restrict__ RI,
                         const float* __restrict__ vdw, float* __restrict__ slot,
                         int N, int A, int TJ, int p) {
    // map flat p -> (bi, bj): for row bi, bj ranges over [RATIO*bi, TJ)
    int bi = 0, rem = p;
    while (true) {
        int cnt = TJ - RATIO * bi;
        cnt = cnt > 0 ? cnt : 0;
        if (rem < cnt) break;
        rem -= cnt; ++bi;
    }
    int bj = RATIO * bi + rem;

    __shared__ float4 sPos[JTL];   // x,y,z, vdwEff (= vdw-1.5, or -1e30 if masked/pad)
    __shared__ float sMask[JTL];
    __shared__ int sRM[JTL];       // (ri<<5) | slot | (cys-SG ? 16 : 0)

    int t = threadIdx.x;
    if (t < JTL) {
        int j = bj * JTL + t;
        if (j < A) {
            int res = j / 14;
            int sl = j - res * 14;
            int rt = RT[res];
            int rtc = rt < 20 ? rt : 20;
            float mj = M[j];
            float w = (mj == 0.f) ? -1e30f : (vdw[rtc * 14 + sl] - 1.5f);
            sPos[t] = make_float4(P[j * 3], P[j * 3 + 1], P[j * 3 + 2], w);
            sMask[t] = mj;
            sRM[t] = (RI[res] << 5) | sl | (((rt == 4) && (sl == 5)) ? 16 : 0);
        } else {
            sPos[t] = make_float4(1e30f, 1e30f, 1e30f, -1e30f);
            sMask[t] = 0.f; sRM[t] = 0;
        }
    }
    __syncthreads();

    // two i atoms per thread
    int i0 = bi * IT + t;
    int i1 = i0 + 256;
    float xi0 = 0.f, yi0 = 0.f, zi0 = 0.f, vi0 = -1e30f, mi0 = 0.f;
    float xi1 = 0.f, yi1 = 0.f, zi1 = 0.f, vi1 = -1e30f, mi1 = 0.f;
    int iri0 = 0, iri1 = 0;
    bool icys0 = false, icys1 = false;
    int isl0 = -1, isl1 = -1;
    if (i0 < A) {
        int res = i0 / 14; isl0 = i0 - res * 14;
        int rt = RT[res]; int rtc = rt < 20 ? rt : 20;
        vi0 = vdw[rtc * 14 + isl0];
        xi0 = P[i0 * 3]; yi0 = P[i0 * 3 + 1]; zi0 = P[i0 * 3 + 2];
        mi0 = M[i0]; iri0 = RI[res]; icys0 = (rt == 4) && (isl0 == 5);
        if (mi0 == 0.f) vi0 = -1e30f;
    }
    if (i1 < A) {
        int res = i1 / 14; isl1 = i1 - res * 14;
        int rt = RT[res]; int rtc = rt < 20 ? rt : 20;
        vi1 = vdw[rtc * 14 + isl1];
        xi1 = P[i1 * 3]; yi1 = P[i1 * 3 + 1]; zi1 = P[i1 * 3 + 2];
        mi1 = M[i1]; iri1 = RI[res]; icys1 = (rt == 4) && (isl1 == 5);
        if (mi1 == 0.f) vi1 = -1e30f;
    }

    float sum = 0.f;
    int jbase_g = bj * JTL;
    for (int base = 0; base < JTL; base += 8) {
        float4 r[8];
#pragma unroll
        for (int k = 0; k < 8; ++k) r[k] = sPos[base + k];
#pragma unroll
        for (int k = 0; k < 8; ++k) {
            float w = r[k].w;
            // chain 0
            {
                float dx = xi0 - r[k].x, dy = yi0 - r[k].y, dz = zi0 - r[k].z;
                float d2 = dx * dx + dy * dy + dz * dz;
                float s = vi0 + w;
                if (s > 0.f && d2 < s * s) {
                    int jj = base + k, jg = jbase_g + jj;
                    if (i0 < jg) {
                        int rm = sRM[jj];
                        int jri = rm >> 5;
                        if (iri0 != jri) {
                            int dj = jri - iri0;
                            int jsl = rm & 15;
                            bool cn = (isl0 == 2 && jsl == 0 && dj == 1) ||
                                      (isl0 == 0 && jsl == 2 && dj == -1);
                            bool ssb = icys0 && (rm & 16);
                            if (!cn && !ssb)
                                sum += (s - sqrtf(d2 + 1e-8f)) * mi0 * sMask[jj];
                        }
                    }
                }
            }
            // chain 1
            {
                float dx = xi1 - r[k].x, dy = yi1 - r[k].y, dz = zi1 - r[k].z;
                float d2 = dx * dx + dy * dy + dz * dz;
                float s = vi1 + w;
                if (s > 0.f && d2 < s * s) {
                    int jj = base + k, jg = jbase_g + jj;
                    if (i1 < jg) {
                        int rm = sRM[jj];
                        int jri = rm >> 5;
                        if (iri1 != jri) {
                            int dj = jri - iri1;
                            int jsl = rm & 15;
                            bool cn = (isl1 == 2 && jsl == 0 && dj == 1) ||
                                      (isl1 == 0 && jsl == 2 && dj == -1);
                            bool ssb = icys1 && (rm & 16);
                            if (!cn && !ssb)
                                sum += (s - sqrtf(d2 + 1e-8f)) * mi1 * sMask[jj];
                        }
                    }
                }
            }
        }
    }
    sum = wave_reduce_add(sum);
    __shared__ float red3[4];
    int lane = t & 63, wid = t >> 6;
    if (lane == 0) red3[wid] = sum;
    __syncthreads();
    if (t == 0) *slot = red3[0] + red3[1] + red3[2] + red3[3];
}

__global__ __launch_bounds__(256, 4) void fused_kernel(
        const float* __restrict__ pos, const float* __restrict__ am,
        const int* __restrict__ rtypes, const int* __restrict__ rindex,
        const float* __restrict__ vdw, const float* __restrict__ lbt,
        const float* __restrict__ ubt, float* __restrict__ ws,
        float* __restrict__ out,
        int N, int A, int TJ, int CB, int NBP, int stride) {
    int b = blockIdx.y;
    const float* P = pos + (size_t)b * A * 3;
    const float* M = am + (size_t)b * A;
    const int* RT = rtypes + (size_t)b * N;
    const int* RI = rindex + (size_t)b * N;
    float* W = ws + (size_t)b * stride;
    int bid = blockIdx.x;
    if (bid < CB) {
        do_clash(P, M, RT, RI, vdw, &W[bid], N, A, TJ, bid);
    } else if (bid < NBP) {
        do_within(pos, am, rtypes, lbt, ubt, &W[bid], N, b, bid - CB);
    } else {
        do_bonds(P, M, RT, RI, &W[NBP], N, A);
    }

    __threadfence();                 // device-scope release of partial-slot stores
    cg::this_grid().sync();          // grid-wide barrier (cooperative launch)

    if (bid == 0) {                  // block (0,b) finalizes batch b
        float pairs = 0.f;
        for (int i = threadIdx.x; i < NBP; i += blockDim.x) pairs += W[i];
        pairs = wave_reduce_add(pairs);
        __shared__ float redf[4];
        int lane = threadIdx.x & 63, wid = threadIdx.x >> 6;
        if (lane == 0) redf[wid] = pairs;
        __syncthreads();
        if (threadIdx.x == 0) {
            float P2 = redf[0] + redf[1] + redf[2] + redf[3];
            const float* T7 = W + NBP;
            float na = fmaxf(T7[6], 1e-6f);
            float loss = T7[0] / (T7[1] + EPS) + T7[2] / (T7[3] + EPS)
                       + T7[4] / (T7[5] + EPS) + 2.f * P2 / na;
            out[b] = loss;
        }
    }
}

extern "C" void kernel_launch(void* const* d_in, const int* in_sizes, int n_in,
                              void* d_out, int out_size, void* d_ws, size_t ws_size,
                              hipStream_t stream) {
    const float* pos = (const float*)d_in[0];
    const float* am = (const float*)d_in[1];
    const int* rtypes = (const int*)d_in[2];
    const int* rindex = (const int*)d_in[3];
    const float* vdw = (const float*)d_in[4];
    const float* lbt = (const float*)d_in[5];
    const float* ubt = (const float*)d_in[6];
    float* out = (float*)d_out;
    float* ws = (float*)d_ws;

    int B = out_size;
    int N = in_sizes[2] / B;
    int A = N * 14;
    int TI = (A + IT - 1) / IT;
    int TJ = (A + JTL - 1) / JTL;
    int CB = 0;
    for (int bi = 0; bi < TI; ++bi) {
        int c = TJ - RATIO * bi;
        if (c > 0) CB += c;
    }
    int NBP = CB + WB;          // pair-partial slots
    int stride = NBP + 7;       // + bonds tail + mask total

    dim3 grid(NBP + 1, B);
    dim3 block(256);
    void* args[] = {(void*)&pos, (void*)&am, (void*)&rtypes, (void*)&rindex,
                    (void*)&vdw, (void*)&lbt, (void*)&ubt, (void*)&ws, (void*)&out,
                    (void*)&N, (void*)&A, (void*)&TJ, (void*)&CB, (void*)&NBP,
                    (void*)&stride};
    hipLaunchCooperativeKernel((const void*)fused_kernel, grid, block, args, 0, stream);
}

// Round 7
// 86.262 us; speedup vs baseline: 2.8644x; 2.8644x over previous
//
#include <hip/hip_runtime.h>

#define EPS 1e-6f
#define IT 512           // clash i-tile (2 per thread, 256 threads)
#define JTL 64           // clash j-tile (LDS resident)
#define RATIO 8          // IT / JTL
#define WB 64            // within-residue blocks

static __device__ __forceinline__ float wave_reduce_add(float v) {
#pragma unroll
    for (int o = 32; o > 0; o >>= 1) v += __shfl_down(v, o, 64);
    return v;
}

// ws layout per batch (stride = NBP + 7 floats):
//   [0, NBP)       per-block pair-loss partials (clash + within blocks)
//   [NBP, NBP+6)   bonds: cn_num cn_den cacn_num cacn_den cnca_num cnca_den
//   [NBP+6]        atom-mask total
// Every slot written unconditionally every launch -> no zero-init needed.
// NOTE (r6 lesson): do NOT fuse the final reduce via cg::grid().sync() —
// the grid barrier costs ~160 µs on gfx950 (global spin), vs ~3 µs for a
// second launch.

__device__ void do_bonds(const float* __restrict__ P, const float* __restrict__ M,
                         const int* __restrict__ RT, const int* __restrict__ RI,
                         float* __restrict__ Wtail, int N, int A) {
    float n0 = 0.f, de0 = 0.f, n1 = 0.f, de1 = 0.f, n2 = 0.f, de2 = 0.f;
    for (int i = threadIdx.x; i < N - 1; i += blockDim.x) {
        float no_gap = (RI[i + 1] - RI[i] == 1) ? 1.f : 0.f;
        const float* ca0 = P + i * 42 + 3;
        const float* c0  = P + i * 42 + 6;
        const float* nn  = P + (i + 1) * 42 + 0;
        const float* ca1 = P + (i + 1) * 42 + 3;
        float m_ca0 = M[i * 14 + 1], m_c0 = M[i * 14 + 2];
        float m_nn = M[(i + 1) * 14 + 0], m_ca1 = M[(i + 1) * 14 + 1];

        float bx = nn[0] - c0[0], by = nn[1] - c0[1], bz = nn[2] - c0[2];
        float c_n_len = sqrtf(bx * bx + by * by + bz * bz + EPS);
        float pro = (RT[i + 1] == 14) ? 1.f : 0.f;
        float gt_len = (1.f - pro) * 1.329f + pro * 1.341f;
        float gt_std = (1.f - pro) * 0.014f + pro * 0.016f;
        float cnm = m_c0 * m_nn * no_gap;
        float dl = c_n_len - gt_len;
        float cne = sqrtf(dl * dl + EPS);
        n0 += cnm * fmaxf(cne - 12.f * gt_std, 0.f);
        de0 += cnm;

        float ax = ca0[0] - c0[0], ay = ca0[1] - c0[1], az = ca0[2] - c0[2];
        float ca_c_len = sqrtf(ax * ax + ay * ay + az * az + EPS);
        float ex = ca1[0] - nn[0], ey = ca1[1] - nn[1], ez = ca1[2] - nn[2];
        float n_ca_len = sqrtf(ex * ex + ey * ey + ez * ez + EPS);
        float inv_cn = 1.f / c_n_len, inv_ac = 1.f / ca_c_len, inv_nc = 1.f / n_ca_len;
        float ux = bx * inv_cn, uy = by * inv_cn, uz = bz * inv_cn;
        float cx = ax * inv_ac, cy = ay * inv_ac, cz = az * inv_ac;
        float wx = ex * inv_nc, wy = ey * inv_nc, wz = ez * inv_nc;

        float cacn = cx * ux + cy * uy + cz * uz;
        float m1 = m_ca0 * m_c0 * m_nn * no_gap;
        float t1 = cacn + 0.5203f;
        float e1 = sqrtf(t1 * t1 + EPS);
        n1 += m1 * fmaxf(e1 - 12.f * 0.0353f, 0.f);
        de1 += m1;

        float cnca = -(ux * wx + uy * wy + uz * wz);
        float m2 = m_c0 * m_nn * m_ca1 * no_gap;
        float t2 = cnca + 0.4473f;
        float e2 = sqrtf(t2 * t2 + EPS);
        n2 += m2 * fmaxf(e2 - 12.f * 0.0311f, 0.f);
        de2 += m2;
    }
    // atom-mask total (concurrent with clash blocks)
    float ms = 0.f;
    int A4 = A >> 2;
    const float4* M4 = (const float4*)M;
    for (int i = threadIdx.x; i < A4; i += blockDim.x) {
        float4 v = M4[i];
        ms += v.x + v.y + v.z + v.w;
    }
    if (threadIdx.x == 0) for (int i = A4 << 2; i < A; ++i) ms += M[i];

    n0 = wave_reduce_add(n0); de0 = wave_reduce_add(de0);
    n1 = wave_reduce_add(n1); de1 = wave_reduce_add(de1);
    n2 = wave_reduce_add(n2); de2 = wave_reduce_add(de2);
    ms = wave_reduce_add(ms);
    __shared__ float redb[28];
    int lane = threadIdx.x & 63, wid = threadIdx.x >> 6;
    if (lane == 0) {
        redb[wid * 7 + 0] = n0; redb[wid * 7 + 1] = de0; redb[wid * 7 + 2] = n1;
        redb[wid * 7 + 3] = de1; redb[wid * 7 + 4] = n2; redb[wid * 7 + 5] = de2;
        redb[wid * 7 + 6] = ms;
    }
    __syncthreads();
    if (threadIdx.x < 7) {
        Wtail[threadIdx.x] = redb[threadIdx.x] + redb[7 + threadIdx.x]
                           + redb[14 + threadIdx.x] + redb[21 + threadIdx.x];
    }
}

__device__ void do_within(const float* __restrict__ pos, const float* __restrict__ am,
                          const int* __restrict__ rtypes,
                          const float* __restrict__ lbt, const float* __restrict__ ubt,
                          float* __restrict__ slot, int N, int b, int wblk) {
    int total = N * 196;
    float sum = 0.f;
    for (int idx = wblk * blockDim.x + threadIdx.x; idx < total; idx += WB * blockDim.x) {
        int n = idx / 196;
        int p = idx - n * 196;
        int i = p / 14;
        int j = p - i * 14;
        if (i == j) continue;
        size_t bn = (size_t)b * N + n;
        int rt = rtypes[bn]; rt = rt < 20 ? rt : 20;
        const float* pi = pos + bn * 42 + i * 3;
        const float* pj = pos + bn * 42 + j * 3;
        float dx = pi[0] - pj[0], dy = pi[1] - pj[1], dz = pi[2] - pj[2];
        float d = sqrtf(dx * dx + dy * dy + dz * dz + 1e-8f);
        float lb = lbt[rt * 196 + p], ub = ubt[rt * 196 + p];
        float gate = (lb > 0.f || ub > 0.f) ? 1.f : 0.f;
        float m = am[bn * 14 + i] * am[bn * 14 + j] * gate;
        sum += (fmaxf(lb - d, 0.f) + fmaxf(d - ub, 0.f)) * m;
    }
    sum = wave_reduce_add(sum);
    __shared__ float red2[4];
    int lane = threadIdx.x & 63, wid = threadIdx.x >> 6;
    if (lane == 0) red2[wid] = sum;
    __syncthreads();
    if (threadIdx.x == 0) *slot = red2[0] + red2[1] + red2[2] + red2[3];
}

__device__ void do_clash(const float* __restrict__ P, const float* __restrict__ M,
                         const int* __restrict__ RT, const int* __restrict__ RI,
                         const float* __restrict__ vdw, float* __restrict__ slot,
                         int N, int A, int TJ, int p) {
    // map flat p -> (bi, bj): for row bi, bj ranges over [RATIO*bi, TJ)
    int bi = 0, rem = p;
    while (true) {
        int cnt = TJ - RATIO * bi;
        cnt = cnt > 0 ? cnt : 0;
        if (rem < cnt) break;
        rem -= cnt; ++bi;
    }
    int bj = RATIO * bi + rem;

    __shared__ float4 sPos[JTL];   // x,y,z, vdwEff (= vdw-1.5, or -1e30 if masked/pad)
    __shared__ float sMask[JTL];
    __shared__ int sRM[JTL];       // (ri<<5) | slot | (cys-SG ? 16 : 0)

    int t = threadIdx.x;
    if (t < JTL) {
        int j = bj * JTL + t;
        if (j < A) {
            int res = j / 14;
            int sl = j - res * 14;
            int rt = RT[res];
            int rtc = rt < 20 ? rt : 20;
            float mj = M[j];
            float w = (mj == 0.f) ? -1e30f : (vdw[rtc * 14 + sl] - 1.5f);
            sPos[t] = make_float4(P[j * 3], P[j * 3 + 1], P[j * 3 + 2], w);
            sMask[t] = mj;
            sRM[t] = (RI[res] << 5) | sl | (((rt == 4) && (sl == 5)) ? 16 : 0);
        } else {
            sPos[t] = make_float4(1e30f, 1e30f, 1e30f, -1e30f);
            sMask[t] = 0.f; sRM[t] = 0;
        }
    }
    __syncthreads();

    // two i atoms per thread
    int i0 = bi * IT + t;
    int i1 = i0 + 256;
    float xi0 = 0.f, yi0 = 0.f, zi0 = 0.f, vi0 = -1e30f, mi0 = 0.f;
    float xi1 = 0.f, yi1 = 0.f, zi1 = 0.f, vi1 = -1e30f, mi1 = 0.f;
    int iri0 = 0, iri1 = 0;
    bool icys0 = false, icys1 = false;
    int isl0 = -1, isl1 = -1;
    if (i0 < A) {
        int res = i0 / 14; isl0 = i0 - res * 14;
        int rt = RT[res]; int rtc = rt < 20 ? rt : 20;
        vi0 = vdw[rtc * 14 + isl0];
        xi0 = P[i0 * 3]; yi0 = P[i0 * 3 + 1]; zi0 = P[i0 * 3 + 2];
        mi0 = M[i0]; iri0 = RI[res]; icys0 = (rt == 4) && (isl0 == 5);
        if (mi0 == 0.f) vi0 = -1e30f;
    }
    if (i1 < A) {
        int res = i1 / 14; isl1 = i1 - res * 14;
        int rt = RT[res]; int rtc = rt < 20 ? rt : 20;
        vi1 = vdw[rtc * 14 + isl1];
        xi1 = P[i1 * 3]; yi1 = P[i1 * 3 + 1]; zi1 = P[i1 * 3 + 2];
        mi1 = M[i1]; iri1 = RI[res]; icys1 = (rt == 4) && (isl1 == 5);
        if (mi1 == 0.f) vi1 = -1e30f;
    }

    float sum = 0.f;
    int jbase_g = bj * JTL;
    for (int base = 0; base < JTL; base += 8) {
        float4 r[8];
#pragma unroll
        for (int k = 0; k < 8; ++k) r[k] = sPos[base + k];
#pragma unroll
        for (int k = 0; k < 8; ++k) {
            float w = r[k].w;
            // chain 0
            {
                float dx = xi0 - r[k].x, dy = yi0 - r[k].y, dz = zi0 - r[k].z;
                float d2 = dx * dx + dy * dy + dz * dz;
                float s = vi0 + w;
                if (s > 0.f && d2 < s * s) {
                    int jj = base + k, jg = jbase_g + jj;
                    if (i0 < jg) {
                        int rm = sRM[jj];
                        int jri = rm >> 5;
                        if (iri0 != jri) {
                            int dj = jri - iri0;
                            int jsl = rm & 15;
                            bool cn = (isl0 == 2 && jsl == 0 && dj == 1) ||
                                      (isl0 == 0 && jsl == 2 && dj == -1);
                            bool ssb = icys0 && (rm & 16);
                            if (!cn && !ssb)
                                sum += (s - sqrtf(d2 + 1e-8f)) * mi0 * sMask[jj];
                        }
                    }
                }
            }
            // chain 1
            {
                float dx = xi1 - r[k].x, dy = yi1 - r[k].y, dz = zi1 - r[k].z;
                float d2 = dx * dx + dy * dy + dz * dz;
                float s = vi1 + w;
                if (s > 0.f && d2 < s * s) {
                    int jj = base + k, jg = jbase_g + jj;
                    if (i1 < jg) {
                        int rm = sRM[jj];
                        int jri = rm >> 5;
                        if (iri1 != jri) {
                            int dj = jri - iri1;
                            int jsl = rm & 15;
                            bool cn = (isl1 == 2 && jsl == 0 && dj == 1) ||
                                      (isl1 == 0 && jsl == 2 && dj == -1);
                            bool ssb = icys1 && (rm & 16);
                            if (!cn && !ssb)
                                sum += (s - sqrtf(d2 + 1e-8f)) * mi1 * sMask[jj];
                        }
                    }
                }
            }
        }
    }
    sum = wave_reduce_add(sum);
    __shared__ float red3[4];
    int lane = t & 63, wid = t >> 6;
    if (lane == 0) red3[wid] = sum;
    __syncthreads();
    if (t == 0) *slot = red3[0] + red3[1] + red3[2] + red3[3];
}

__global__ __launch_bounds__(256, 4) void main_kernel(
        const float* __restrict__ pos, const float* __restrict__ am,
        const int* __restrict__ rtypes, const int* __restrict__ rindex,
        const float* __restrict__ vdw, const float* __restrict__ lbt,
        const float* __restrict__ ubt, float* __restrict__ ws,
        int N, int A, int TJ, int CB, int NBP, int stride) {
    int b = blockIdx.y;
    const float* P = pos + (size_t)b * A * 3;
    const float* M = am + (size_t)b * A;
    const int* RT = rtypes + (size_t)b * N;
    const int* RI = rindex + (size_t)b * N;
    float* W = ws + (size_t)b * stride;
    int bid = blockIdx.x;
    if (bid < CB) {
        do_clash(P, M, RT, RI, vdw, &W[bid], N, A, TJ, bid);
    } else if (bid < NBP) {
        do_within(pos, am, rtypes, lbt, ubt, &W[bid], N, b, bid - CB);
    } else {
        do_bonds(P, M, RT, RI, &W[NBP], N, A);
    }
}

__global__ __launch_bounds__(256) void final_kernel(
        const float* __restrict__ ws, float* __restrict__ out,
        int NBP, int stride) {
    int b = blockIdx.x;
    const float* W = ws + (size_t)b * stride;
    float pairs = 0.f;
    for (int i = threadIdx.x; i < NBP; i += blockDim.x) pairs += W[i];
    pairs = wave_reduce_add(pairs);
    __shared__ float red[4];
    int lane = threadIdx.x & 63, wid = threadIdx.x >> 6;
    if (lane == 0) red[wid] = pairs;
    __syncthreads();
    if (threadIdx.x == 0) {
        float P2 = red[0] + red[1] + red[2] + red[3];
        const float* T7 = W + NBP;
        float na = fmaxf(T7[6], 1e-6f);
        float loss = T7[0] / (T7[1] + EPS) + T7[2] / (T7[3] + EPS)
                   + T7[4] / (T7[5] + EPS) + 2.f * P2 / na;
        out[b] = loss;
    }
}

extern "C" void kernel_launch(void* const* d_in, const int* in_sizes, int n_in,
                              void* d_out, int out_size, void* d_ws, size_t ws_size,
                              hipStream_t stream) {
    const float* pos = (const float*)d_in[0];
    const float* am = (const float*)d_in[1];
    const int* rtypes = (const int*)d_in[2];
    const int* rindex = (const int*)d_in[3];
    const float* vdw = (const float*)d_in[4];
    const float* lbt = (const float*)d_in[5];
    const float* ubt = (const float*)d_in[6];
    float* out = (float*)d_out;
    float* ws = (float*)d_ws;

    int B = out_size;
    int N = in_sizes[2] / B;
    int A = N * 14;
    int TI = (A + IT - 1) / IT;
    int TJ = (A + JTL - 1) / JTL;
    int CB = 0;
    for (int bi = 0; bi < TI; ++bi) {
        int c = TJ - RATIO * bi;
        if (c > 0) CB += c;
    }
    int NBP = CB + WB;          // pair-partial slots
    int stride = NBP + 7;       // + bonds tail + mask total

    dim3 grid(NBP + 1, B);
    main_kernel<<<grid, 256, 0, stream>>>(pos, am, rtypes, rindex, vdw, lbt, ubt,
                                          ws, N, A, TJ, CB, NBP, stride);
    final_kernel<<<B, 256, 0, stream>>>(ws, out, NBP, stride);
}